// Round 8
// baseline (181.611 us; speedup 1.0000x reference)
//
#include <hip/hip_runtime.h>

#define N_NODES 50000
#define N_EDGES 800000
#define D_EDGE 64
#define D_NODE 64
#define D_IN 192
#define D_HID 256
#define D_OUT 64

#define BS 128            // nodes per bucket
#define NBK 391           // buckets per side (391*128 = 50048 >= 50000)
#define NC (2*NBK)        // 782 bucket-sides (in-side then out-side)

typedef __attribute__((ext_vector_type(8))) short bf16x8;
typedef __attribute__((ext_vector_type(4))) float f32x4;

__device__ inline ushort f2bf(float f) {
    union { float f; unsigned u; } v; v.f = f;
    unsigned r = v.u + 0x7fff + ((v.u >> 16) & 1);   // round-to-nearest-even
    return (ushort)(r >> 16);
}

// ---------------------------------------------------------------------------
// K0: convert edge_feat f32 -> bf16 rows (128 B/row, one cache line).
// Pure streaming: each thread converts 16 floats (64 B read, 32 B write).
// ---------------------------------------------------------------------------
__global__ __launch_bounds__(256) void conv_kernel(
    const float* __restrict__ ef, ushort* __restrict__ efb) {
    size_t t = (size_t)blockIdx.x * 256 + threadIdx.x;
    size_t base = t * 16;
    if (base >= (size_t)N_EDGES * D_EDGE) return;
    const f32x4* s = (const f32x4*)(ef + base);
    f32x4 v0 = s[0], v1 = s[1], v2 = s[2], v3 = s[3];
    union { bf16x8 v; ushort u[8]; } o0, o1;
#pragma unroll
    for (int j = 0; j < 4; j++) {
        o0.u[j] = f2bf(v0[j]); o0.u[4 + j] = f2bf(v1[j]);
        o1.u[j] = f2bf(v2[j]); o1.u[4 + j] = f2bf(v3[j]);
    }
    bf16x8* d = (bf16x8*)(efb + base);
    d[0] = o0.v; d[1] = o1.v;
}

// ---------------------------------------------------------------------------
// K1: coarse histogram over NC (side,bucket) counters, LDS-aggregated.
// ---------------------------------------------------------------------------
__global__ __launch_bounds__(256) void chist_kernel(
    const int* __restrict__ senders, const int* __restrict__ receivers,
    int* __restrict__ gcnt) {
    __shared__ int lcnt[NC];
    for (int i = threadIdx.x; i < NC; i += 256) lcnt[i] = 0;
    __syncthreads();
    const int stride = gridDim.x * 256;
    const int nvec = N_EDGES / 4;   // 200000
    const int4* rv = (const int4*)receivers;
    const int4* sv = (const int4*)senders;
    for (int i = blockIdx.x * 256 + threadIdx.x; i < nvec; i += stride) {
        int4 r = rv[i], s = sv[i];
        atomicAdd(&lcnt[r.x / BS], 1);
        atomicAdd(&lcnt[r.y / BS], 1);
        atomicAdd(&lcnt[r.z / BS], 1);
        atomicAdd(&lcnt[r.w / BS], 1);
        atomicAdd(&lcnt[NBK + s.x / BS], 1);
        atomicAdd(&lcnt[NBK + s.y / BS], 1);
        atomicAdd(&lcnt[NBK + s.z / BS], 1);
        atomicAdd(&lcnt[NBK + s.w / BS], 1);
    }
    __syncthreads();
    for (int i = threadIdx.x; i < NC; i += 256) {
        int c = lcnt[i];
        if (c) atomicAdd(&gcnt[i], c);
    }
}

// ---------------------------------------------------------------------------
// K2: exclusive scan of the NC bucket counts -> coffs[NC+1] + cursor copy.
// ---------------------------------------------------------------------------
__global__ __launch_bounds__(1024) void cscan_kernel(
    const int* __restrict__ gcnt, int* __restrict__ coffs, int* __restrict__ gcur) {
    __shared__ int s[1024];
    const int t = threadIdx.x;
    int v = (t < NC) ? gcnt[t] : 0;
    s[t] = v;
    __syncthreads();
    for (int off = 1; off < 1024; off <<= 1) {
        int u = (t >= off) ? s[t - off] : 0;
        __syncthreads();
        s[t] += u;
        __syncthreads();
    }
    int excl = s[t] - v;
    if (t < NC) { coffs[t] = excl; gcur[t] = excl; }
    if (t == NC - 1) coffs[NC] = excl + v;   // == 2*N_EDGES
}

// ---------------------------------------------------------------------------
// K3: bin — write (node, edge) pairs into per-bucket regions. Two-phase
// LDS ranking so global writes stream into NC dense frontiers.
// ---------------------------------------------------------------------------
#define F1_EPT 16
#define F1_BLK_EDGES (256 * F1_EPT)   // 4096
__global__ __launch_bounds__(256) void bin_kernel(
    const int* __restrict__ senders, const int* __restrict__ receivers,
    int* __restrict__ gcur, int2* __restrict__ pair_buf) {
    __shared__ int lcnt[NC];
    __shared__ int lbase[NC];
    for (int i = threadIdx.x; i < NC; i += 256) lcnt[i] = 0;
    __syncthreads();
    const int base_e = blockIdx.x * F1_BLK_EDGES;
    int rr[F1_EPT], ss[F1_EPT], rkr[F1_EPT], rks[F1_EPT];
#pragma unroll
    for (int j = 0; j < F1_EPT; j++) {
        int e = base_e + j * 256 + threadIdx.x;
        if (e < N_EDGES) {
            int r = receivers[e], sd = senders[e];
            rr[j] = r; ss[j] = sd;
            rkr[j] = atomicAdd(&lcnt[r / BS], 1);
            rks[j] = atomicAdd(&lcnt[NBK + sd / BS], 1);
        } else {
            rr[j] = -1;
        }
    }
    __syncthreads();
    for (int i = threadIdx.x; i < NC; i += 256) {
        int c = lcnt[i];
        lbase[i] = c ? atomicAdd(&gcur[i], c) : 0;
    }
    __syncthreads();
#pragma unroll
    for (int j = 0; j < F1_EPT; j++) {
        if (rr[j] >= 0) {
            int e = base_e + j * 256 + threadIdx.x;
            pair_buf[lbase[rr[j] / BS] + rkr[j]] = make_int2(rr[j], e);
            pair_buf[lbase[NBK + ss[j] / BS] + rks[j]] = make_int2(ss[j], e);
        }
    }
}

// ---------------------------------------------------------------------------
// K4: reorder — one block per bucket-side. Sort the bucket's pairs by node
// into a fine CSR edge-id array (dense-span writes only). Emits offsets.
// ---------------------------------------------------------------------------
__global__ __launch_bounds__(256) void reorder_kernel(
    const int2* __restrict__ pair_buf, const int* __restrict__ coffs,
    int* __restrict__ eidx, int* __restrict__ offs_in, int* __restrict__ offs_out) {
    __shared__ int cur[BS];
    __shared__ int ss[256];
    const int i = blockIdx.x;
    const int side = (i >= NBK) ? 1 : 0;
    const int node_base = (side ? i - NBK : i) * BS;
    const int t = threadIdx.x;
    if (t < BS) cur[t] = 0;
    __syncthreads();
    const int p0 = coffs[i], p1 = coffs[i + 1];
    for (int p = p0 + t; p < p1; p += 256)
        atomicAdd(&cur[pair_buf[p].x - node_base], 1);
    __syncthreads();
    int v = (t < BS) ? cur[t] : 0;
    ss[t] = v;
    __syncthreads();
    for (int off = 1; off < 256; off <<= 1) {
        int u = (t >= off) ? ss[t - off] : 0;
        __syncthreads();
        ss[t] += u;
        __syncthreads();
    }
    int ex = ss[t] - v;   // exclusive prefix within bucket
    int* offs = side ? offs_out : offs_in;
    if (t < BS) {
        cur[t] = ex;
        int node = node_base + t;
        if (node < N_NODES) offs[node] = p0 + ex;
    }
    if (t == 0 && node_base + BS >= N_NODES) offs[N_NODES] = p1;  // sentinel (last bucket)
    __syncthreads();
    for (int p = p0 + t; p < p1; p += 256) {
        int2 q = pair_buf[p];
        int rk = atomicAdd(&cur[q.x - node_base], 1);
        eidx[p0 + rk] = q.y;
    }
}

// ---------------------------------------------------------------------------
// K5: gather — one wave per (node, side), bf16 rows (128 B = 1 line).
// Lane loads 16 B (8 bf16): 8 lanes/row -> wave covers 8 rows per load,
// 2-deep unroll -> 16 rows in flight. shfl_xor reduce across 8 row-groups.
// ---------------------------------------------------------------------------
__device__ inline void addbf(float* acc, uint4 w) {
    acc[0] += __uint_as_float(w.x << 16);
    acc[1] += __uint_as_float(w.x & 0xffff0000u);
    acc[2] += __uint_as_float(w.y << 16);
    acc[3] += __uint_as_float(w.y & 0xffff0000u);
    acc[4] += __uint_as_float(w.z << 16);
    acc[5] += __uint_as_float(w.z & 0xffff0000u);
    acc[6] += __uint_as_float(w.w << 16);
    acc[7] += __uint_as_float(w.w & 0xffff0000u);
}

__global__ __launch_bounds__(256) void gather_kernel(
    const ushort* __restrict__ efb,     // [N_EDGES][64] bf16
    const int* __restrict__ offs_in, const int* __restrict__ offs_out,
    const int* __restrict__ eidx,
    ushort* __restrict__ x) {           // [N_NODES][128] bf16
    int task = blockIdx.x * 4 + (threadIdx.x >> 6);
    if (task >= 2 * N_NODES) return;
    const int lane = threadIdx.x & 63;
    const int sub = lane >> 3;          // row-group 0..7
    const int c8 = (lane & 7) * 8;      // column base (8 lanes span a 64-col row)
    const int node = task >> 1;
    const int side = task & 1;
    const int* offs = side ? offs_out : offs_in;
    const int b = offs[node], e = offs[node + 1];
    float acc[8] = {0.f, 0.f, 0.f, 0.f, 0.f, 0.f, 0.f, 0.f};
    int i = b + sub;
    for (; i + 8 < e; i += 16) {        // 2 rows per group in flight
        int r0 = eidx[i], r1 = eidx[i + 8];
        uint4 w0 = *(const uint4*)(efb + (size_t)r0 * D_EDGE + c8);
        uint4 w1 = *(const uint4*)(efb + (size_t)r1 * D_EDGE + c8);
        addbf(acc, w0);
        addbf(acc, w1);
    }
    for (; i < e; i += 8) {
        int r = eidx[i];
        uint4 w = *(const uint4*)(efb + (size_t)r * D_EDGE + c8);
        addbf(acc, w);
    }
    // reduce across the 8 row-groups (lanes ^8, ^16, ^32)
#pragma unroll
    for (int j = 0; j < 8; j++) {
        acc[j] += __shfl_xor(acc[j], 8, 64);
        acc[j] += __shfl_xor(acc[j], 16, 64);
        acc[j] += __shfl_xor(acc[j], 32, 64);
    }
    if (sub == 0) {
        union { bf16x8 v; ushort u[8]; } o;
#pragma unroll
        for (int j = 0; j < 8; j++) o.u[j] = f2bf(acc[j]);
        *(bf16x8*)(x + (size_t)node * 128 + side * 64 + c8) = o.v;
    }
}

// ---------------------------------------------------------------------------
// K6: pack W1/W2 (f32) into bf16 fragment-major layout for MFMA B-operands.
// ---------------------------------------------------------------------------
__global__ __launch_bounds__(256) void pack_w_kernel(
    const float* __restrict__ W1, const float* __restrict__ W2,
    ushort* __restrict__ w1p, ushort* __restrict__ w2p) {
    int idx = blockIdx.x * 256 + threadIdx.x;   // 8192 total
    if (idx < 6144) {
        int nt = idx / 384, rem = idx % 384;
        int s = rem / 64, l = rem % 64;
        int g = l >> 4, c = l & 15;
        ushort* dst = w1p + (size_t)idx * 8;
#pragma unroll
        for (int j = 0; j < 8; j++) {
            int k = s * 32 + g * 8 + j;
            dst[j] = f2bf(W1[(size_t)k * D_HID + nt * 16 + c]);
        }
    } else if (idx < 8192) {
        int id2 = idx - 6144;
        int nt = id2 / 512, rem = id2 % 512;
        int s = rem / 64, l = rem % 64;
        int g = l >> 4, c = l & 15;
        ushort* dst = w2p + (size_t)id2 * 8;
#pragma unroll
        for (int j = 0; j < 8; j++) {
            int k = s * 32 + g * 8 + j;
            dst[j] = f2bf(W2[(size_t)k * D_OUT + nt * 16 + c]);
        }
    }
}

// ---------------------------------------------------------------------------
// K7: MFMA MLP. Block = 256 thr (4 waves), 32 nodes (2 mtiles).
// ---------------------------------------------------------------------------
__global__ __launch_bounds__(256) void mlp_mfma_kernel(
    const ushort* __restrict__ x,        // [N][128] bf16
    const float* __restrict__ node_feat, // [N][64]
    const ushort* __restrict__ w1p, const float* __restrict__ b1,
    const ushort* __restrict__ w2p, const float* __restrict__ b2,
    float* __restrict__ out) {
    __shared__ ushort h_lds[32][D_HID + 8];
    const int tid = threadIdx.x;
    const int wave = tid >> 6, lane = tid & 63;
    const int g = lane >> 4, c = lane & 15;
    const int node0 = blockIdx.x * 32;

    f32x4 acc[2][4];
#pragma unroll
    for (int m = 0; m < 2; m++)
#pragma unroll
        for (int q = 0; q < 4; q++) acc[m][q] = (f32x4){0.f, 0.f, 0.f, 0.f};

    const bf16x8* w1v = (const bf16x8*)w1p;
    const bf16x8* w2v = (const bf16x8*)w2p;

    int row0 = node0 + c;      if (row0 > N_NODES - 1) row0 = N_NODES - 1;
    int row1 = node0 + 16 + c; if (row1 > N_NODES - 1) row1 = N_NODES - 1;

#pragma unroll
    for (int s = 0; s < 6; s++) {
        bf16x8 a0, a1;
        if (s < 4) {
            a0 = *(const bf16x8*)(x + (size_t)row0 * 128 + s * 32 + g * 8);
            a1 = *(const bf16x8*)(x + (size_t)row1 * 128 + s * 32 + g * 8);
        } else {
            const float* p0 = node_feat + (size_t)row0 * D_NODE + (s - 4) * 32 + g * 8;
            const float* p1 = node_feat + (size_t)row1 * D_NODE + (s - 4) * 32 + g * 8;
            union { bf16x8 v; ushort u[8]; } t0, t1;
#pragma unroll
            for (int j = 0; j < 8; j++) { t0.u[j] = f2bf(p0[j]); t1.u[j] = f2bf(p1[j]); }
            a0 = t0.v; a1 = t1.v;
        }
#pragma unroll
        for (int q = 0; q < 4; q++) {
            int nt = wave + q * 4;
            bf16x8 b = w1v[(nt * 6 + s) * 64 + lane];
            acc[0][q] = __builtin_amdgcn_mfma_f32_16x16x32_bf16(a0, b, acc[0][q], 0, 0, 0);
            acc[1][q] = __builtin_amdgcn_mfma_f32_16x16x32_bf16(a1, b, acc[1][q], 0, 0, 0);
        }
    }

#pragma unroll
    for (int q = 0; q < 4; q++) {
        int nt = wave + q * 4;
        float bv = b1[nt * 16 + c];
#pragma unroll
        for (int mt = 0; mt < 2; mt++)
#pragma unroll
            for (int r = 0; r < 4; r++) {
                int row = mt * 16 + g * 4 + r;
                h_lds[row][nt * 16 + c] = f2bf(fmaxf(acc[mt][q][r] + bv, 0.f));
            }
    }
    __syncthreads();

    f32x4 acc2[2];
    acc2[0] = (f32x4){0.f, 0.f, 0.f, 0.f};
    acc2[1] = (f32x4){0.f, 0.f, 0.f, 0.f};
#pragma unroll
    for (int s = 0; s < 8; s++) {
        bf16x8 b = w2v[(wave * 8 + s) * 64 + lane];
#pragma unroll
        for (int mt = 0; mt < 2; mt++) {
            bf16x8 a = *(const bf16x8*)(&h_lds[mt * 16 + c][s * 32 + g * 8]);
            acc2[mt] = __builtin_amdgcn_mfma_f32_16x16x32_bf16(a, b, acc2[mt], 0, 0, 0);
        }
    }
    float b2v = b2[wave * 16 + c];
#pragma unroll
    for (int mt = 0; mt < 2; mt++)
#pragma unroll
        for (int r = 0; r < 4; r++) {
            int row = node0 + mt * 16 + g * 4 + r;
            if (row < N_NODES) out[(size_t)row * D_OUT + wave * 16 + c] = acc2[mt][r] + b2v;
        }
}

extern "C" void kernel_launch(void* const* d_in, const int* in_sizes, int n_in,
                              void* d_out, int out_size, void* d_ws, size_t ws_size,
                              hipStream_t stream) {
    const float* node_feat = (const float*)d_in[0];
    const float* edge_feat = (const float*)d_in[1];
    const int* senders     = (const int*)d_in[2];
    const int* receivers   = (const int*)d_in[3];
    const float* W1        = (const float*)d_in[4];
    const float* b1        = (const float*)d_in[5];
    const float* W2        = (const float*)d_in[6];
    const float* b2        = (const float*)d_in[7];
    float* out = (float*)d_out;

    // workspace layout
    ushort* x   = (ushort*)d_ws;                         // 50000*128 bf16 = 12.8 MB
    ushort* efb = x + (size_t)N_NODES * 128;             // 800000*64 bf16 = 102.4 MB
    ushort* w1p = efb + (size_t)N_EDGES * D_EDGE;        // 49152 bf16
    ushort* w2p = w1p + 16 * 6 * 64 * 8;                 // 16384 bf16
    int2* pair_buf = (int2*)(w2p + 4 * 8 * 64 * 8);      // 1.6M pairs = 12.8 MB
    int* eidx     = (int*)(pair_buf + (size_t)2 * N_EDGES); // 1.6M ints = 6.4 MB
    int* offs_in  = eidx + 2 * N_EDGES;                  // N+1
    int* offs_out = offs_in + (N_NODES + 1);             // N+1
    int* gcnt     = offs_out + (N_NODES + 1);            // NC
    int* coffs    = gcnt + NC;                           // NC+1
    int* gcur     = coffs + (NC + 1);                    // NC

    hipMemsetAsync(gcnt, 0, NC * sizeof(int), stream);

    conv_kernel<<<dim3(12500), dim3(256), 0, stream>>>(edge_feat, efb);
    chist_kernel<<<dim3(256), dim3(256), 0, stream>>>(senders, receivers, gcnt);
    cscan_kernel<<<dim3(1), dim3(1024), 0, stream>>>(gcnt, coffs, gcur);
    {
        dim3 grid((N_EDGES + F1_BLK_EDGES - 1) / F1_BLK_EDGES);   // 196
        bin_kernel<<<grid, dim3(256), 0, stream>>>(senders, receivers, gcur, pair_buf);
    }
    reorder_kernel<<<dim3(NC), dim3(256), 0, stream>>>(pair_buf, coffs, eidx,
                                                       offs_in, offs_out);
    pack_w_kernel<<<dim3(32), dim3(256), 0, stream>>>(W1, W2, w1p, w2p);
    {
        const int tasks = 2 * N_NODES;
        dim3 grid((tasks + 3) / 4);
        gather_kernel<<<grid, dim3(256), 0, stream>>>(efb, offs_in, offs_out,
                                                      eidx, x);
    }
    {
        dim3 grid((N_NODES + 31) / 32), block(256);
        mlp_mfma_kernel<<<grid, block, 0, stream>>>(x, node_feat, w1p, b1, w2p, b2, out);
    }
}